// Round 4
// baseline (154.471 us; speedup 1.0000x reference)
//
#include <hip/hip_runtime.h>

typedef unsigned short u16;
typedef unsigned int u32;
typedef __attribute__((ext_vector_type(8))) __bf16 bf16x8;
typedef __attribute__((ext_vector_type(8))) unsigned short u16x8;
typedef __attribute__((ext_vector_type(4))) unsigned short u16x4;
typedef __attribute__((ext_vector_type(2))) unsigned int u32x2;
typedef __attribute__((ext_vector_type(4))) float f32x4;

// ---- bf16 <-> f32 (RNE), bit-exact storage as u16 ----
__device__ __forceinline__ u16 f2bf(float f) {
  u32 u = __builtin_bit_cast(u32, f);
  u += 0x7FFFu + ((u >> 16) & 1u);
  return (u16)(u >> 16);
}
__device__ __forceinline__ float bf2f(u16 h) {
  u32 u = ((u32)h) << 16;
  return __builtin_bit_cast(float, u);
}

// in-register butterfly set over 16 elements, pair mask M
template <int M>
__device__ __forceinline__ void bfly16(float r[16]) {
#pragma unroll
  for (int j = 0; j < 16; ++j)
    if ((j & M) == 0) {
      float a = r[j], b = r[j | M];
      r[j] = a + b;
      r[j | M] = a - b;
    }
}

// ---- K0: conv_w fp32 -> bf16 (Wcat[256][128], rows = p*128+o) ----
__global__ __launch_bounds__(256) void k0_wcat(const float* __restrict__ cw,
                                               u16* __restrict__ wc) {
  int i = blockIdx.x * 256 + threadIdx.x;  // grid = exactly 32768 threads
  wc[i] = f2bf(cw[i]);
}

// ---- K1: block = (b, g: 4-channel group): pad + 2D FWHT on 4 planes,
//          write f2[b][g32][pos][c4] -> contiguous 512B/wave stores ----
__global__ __launch_bounds__(256) void k1_fwht(const float* __restrict__ x,
                                               u16* __restrict__ f2) {
  __shared__ float lds[64 * 68];  // padded stride 68 floats
  const int t = threadIdx.x;
  const int b = blockIdx.x >> 5;
  const int cg = blockIdx.x & 31;
  const int hA = t >> 2, wq = t & 3;   // phase A ownership
  const int hg = t >> 4, rB = t & 15;  // phase B ownership
  const int wC = t & 63, rr = t >> 6;  // phase C ownership
  const bool hok = hA < 56;
  u16x4 outv[16];  // [j][plane], static indexing only

#pragma unroll
  for (int pp = 0; pp < 4; ++pp) {
    const float* xp = x + (size_t)(b * 128 + cg * 4 + pp) * 3136;
    float r[16];
#pragma unroll
    for (int c4 = 0; c4 < 4; ++c4) {
      const int w0 = wq * 16 + c4 * 4;
      if (hok && w0 < 56) {
        const float4 v4 = *(const float4*)(xp + hA * 56 + w0);
        r[c4 * 4 + 0] = v4.x; r[c4 * 4 + 1] = v4.y;
        r[c4 * 4 + 2] = v4.z; r[c4 * 4 + 3] = v4.w;
      } else {
        r[c4 * 4 + 0] = 0.f; r[c4 * 4 + 1] = 0.f;
        r[c4 * 4 + 2] = 0.f; r[c4 * 4 + 3] = 0.f;
      }
    }
    bfly16<1>(r); bfly16<2>(r); bfly16<4>(r); bfly16<8>(r);  // w 1,2,4,8
    if (pp) __syncthreads();  // prior plane's phase-C reads must finish
#pragma unroll
    for (int c4 = 0; c4 < 4; ++c4)
      *(float4*)&lds[hA * 68 + wq * 16 + c4 * 4] =
          make_float4(r[c4 * 4 + 0], r[c4 * 4 + 1], r[c4 * 4 + 2], r[c4 * 4 + 3]);
    __syncthreads();
    // phase B: w stages 16,32 + h stages 1,2
    float q[16];
#pragma unroll
    for (int k = 0; k < 4; ++k)
#pragma unroll
      for (int d = 0; d < 4; ++d)
        q[k * 4 + d] = lds[(hg * 4 + d) * 68 + k * 16 + rB];
    bfly16<4>(q); bfly16<8>(q); bfly16<1>(q); bfly16<2>(q);
#pragma unroll
    for (int k = 0; k < 4; ++k)
#pragma unroll
      for (int d = 0; d < 4; ++d)
        lds[(hg * 4 + d) * 68 + k * 16 + rB] = q[k * 4 + d];  // own addrs
    __syncthreads();
    // phase C: h stages 4,8,16,32
    float s[16];
#pragma unroll
    for (int j = 0; j < 16; ++j) s[j] = lds[(4 * j + rr) * 68 + wC];
    bfly16<1>(s); bfly16<2>(s); bfly16<4>(s); bfly16<8>(s);
#pragma unroll
    for (int j = 0; j < 16; ++j) outv[j][pp] = f2bf(s[j]);
  }
  // f2[b][g][pos][c4]: lane stores 8B at pos*8B, wC consecutive -> 512B/instr
  u16* dst = f2 + ((size_t)(b * 32 + cg) << 14);
#pragma unroll
  for (int j = 0; j < 16; ++j) {
    const int pos = (4 * j + rr) * 64 + wC;
    *(u16x4*)(dst + (size_t)pos * 4) = outv[j];
  }
}

// ---- K2: per (b, 64-pos tile): GEMM from global (no LDS) + v-scale +
//          soft-threshold + p-sum, IN-PLACE: f2[b][g][pos][c4] -> [b][og][pos][o4]
__global__ __launch_bounds__(256) void k2_mix(u16* __restrict__ fg,
                                              const u16* __restrict__ wc,
                                              const float* __restrict__ vv,
                                              const float* __restrict__ tt) {
  const int t = threadIdx.x;
  const int b = blockIdx.x >> 6;
  const int p0 = (blockIdx.x & 63) << 6;
  u16* fb = fg + ((size_t)b << 19);  // 32 groups * 16384 u16
  const int wv = t >> 6, l = t & 63, lr = l & 15, lq = l >> 4;
  f32x4 acc[2][2][4] = {};  // [p][fm(o 16-chunk)][fn(pos 16-chunk)]
#pragma unroll
  for (int q = 0; q < 4; ++q) {  // K chunks of 32
    bf16x8 af[2][2];
#pragma unroll
    for (int fp = 0; fp < 2; ++fp)
#pragma unroll
      for (int fm = 0; fm < 2; ++fm) {
        const int row = fp * 128 + wv * 32 + fm * 16 + lr;  // A row = lane&15
        af[fp][fm] = __builtin_bit_cast(
            bf16x8, *(const u16x8*)(wc + row * 128 + 32 * q + 8 * lq));
      }
#pragma unroll
    for (int fn = 0; fn < 4; ++fn) {
      // B-frag: n = pos = lane&15, k = 32q+8lq+j -> groups 8q+2lq, +1
      const u16* ba =
          fb + ((size_t)(8 * q + 2 * lq) << 14) + (size_t)(p0 + fn * 16 + lr) * 4;
      const u16x4 blo = *(const u16x4*)ba;
      const u16x4 bhi = *(const u16x4*)(ba + 16384);
      u16x8 bj;
      bj[0] = blo[0]; bj[1] = blo[1]; bj[2] = blo[2]; bj[3] = blo[3];
      bj[4] = bhi[0]; bj[5] = bhi[1]; bj[6] = bhi[2]; bj[7] = bhi[3];
      const bf16x8 bq = __builtin_bit_cast(bf16x8, bj);
#pragma unroll
      for (int fp = 0; fp < 2; ++fp)
#pragma unroll
        for (int fm = 0; fm < 2; ++fm)
          acc[fp][fm][fn] = __builtin_amdgcn_mfma_f32_16x16x32_bf16(
              af[fp][fm], bq, acc[fp][fm][fn], 0, 0, 0);
    }
  }
  // all waves' reads of this tile drained (vmcnt(0) at barrier) before stores
  __syncthreads();
  // epilogue: v-scale, soft-threshold, p-sum (in-register), b64 stores
#pragma unroll
  for (int fn = 0; fn < 4; ++fn) {
    const int pos = p0 + fn * 16 + lr;  // D col = lane&15
    const float v0 = vv[pos], v1 = vv[4096 + pos];
    const float t0 = fmaxf(tt[pos], 0.f), t1 = fmaxf(tt[4096 + pos], 0.f);
#pragma unroll
    for (int fm = 0; fm < 2; ++fm) {
      u16 w[4];
#pragma unroll
      for (int rg = 0; rg < 4; ++rg) {  // D row = 4*lq+rg -> o = wv*32+fm*16+lq*4+rg
        const float z0 = v0 * acc[0][fm][fn][rg];
        const float z1 = v1 * acc[1][fm][fn][rg];
        const float s0v = copysignf(fmaxf(fabsf(z0) - t0, 0.f), z0);
        const float s1v = copysignf(fmaxf(fabsf(z1) - t1, 0.f), z1);
        w[rg] = f2bf(s0v + s1v);
      }
      const int og = wv * 8 + fm * 4 + lq;  // o>>2: 4 consecutive o = one group
      u32x2 pk;
      pk[0] = (u32)w[0] | ((u32)w[1] << 16);
      pk[1] = (u32)w[2] | ((u32)w[3] << 16);
      *(u32x2*)(fb + ((size_t)og << 14) + (size_t)pos * 4) = pk;
    }
  }
}

// ---- K3: block = (b, og: 4-o group): 4-plane 2D IWHT (x 1/4096) + crop +
//          residual; reads g[b][og][pos][o4] -> 128B contiguous per thread ----
__global__ __launch_bounds__(256) void k3_iwht(const u16* __restrict__ g,
                                               const float* __restrict__ x,
                                               float* __restrict__ y) {
  __shared__ float lds[64 * 68];
  const int t = threadIdx.x;
  const int b = blockIdx.x >> 5;
  const int og = blockIdx.x & 31;
  const u16* gb = g + ((size_t)(b * 32 + og) << 14);
  const int hA = t >> 2, wq = t & 3;
  const int hg = t >> 4, rB = t & 15;
  const int wC = t & 63, rr = t >> 6;
  // preload phase-A ownership for all 4 planes: 16 b64 loads, 128B contig/thread
  u16x4 inv[16];
#pragma unroll
  for (int e = 0; e < 16; ++e)
    inv[e] = *(const u16x4*)(gb + (size_t)(hA * 64 + wq * 16 + e) * 4);

#pragma unroll
  for (int pp = 0; pp < 4; ++pp) {
    float r[16];
#pragma unroll
    for (int e = 0; e < 16; ++e) r[e] = bf2f(inv[e][pp]);
    bfly16<1>(r); bfly16<2>(r); bfly16<4>(r); bfly16<8>(r);
    if (pp) __syncthreads();
#pragma unroll
    for (int c4 = 0; c4 < 4; ++c4)
      *(float4*)&lds[hA * 68 + wq * 16 + c4 * 4] =
          make_float4(r[c4 * 4 + 0], r[c4 * 4 + 1], r[c4 * 4 + 2], r[c4 * 4 + 3]);
    __syncthreads();
    float q[16];
#pragma unroll
    for (int k = 0; k < 4; ++k)
#pragma unroll
      for (int d = 0; d < 4; ++d)
        q[k * 4 + d] = lds[(hg * 4 + d) * 68 + k * 16 + rB];
    bfly16<4>(q); bfly16<8>(q); bfly16<1>(q); bfly16<2>(q);
#pragma unroll
    for (int k = 0; k < 4; ++k)
#pragma unroll
      for (int d = 0; d < 4; ++d)
        lds[(hg * 4 + d) * 68 + k * 16 + rB] = q[k * 4 + d];
    __syncthreads();
    float s[16];
#pragma unroll
    for (int j = 0; j < 16; ++j) s[j] = lds[(4 * j + rr) * 68 + wC];
    bfly16<1>(s); bfly16<2>(s); bfly16<4>(s); bfly16<8>(s);
    if (wC < 56) {
      const size_t plane = (size_t)(b * 128 + og * 4 + pp) * 3136;
#pragma unroll
      for (int j = 0; j < 14; ++j) {  // h = 4j+rr <= 55
        const int h = 4 * j + rr;
        const size_t idx = plane + (size_t)(h * 56 + wC);
        y[idx] = x[idx] + s[j] * (1.f / 4096.f);
      }
    }
  }
}

extern "C" void kernel_launch(void* const* d_in, const int* in_sizes, int n_in,
                              void* d_out, int out_size, void* d_ws, size_t ws_size,
                              hipStream_t stream) {
  const float* x = (const float*)d_in[0];
  const float* cw = (const float*)d_in[1];
  const float* v = (const float*)d_in[2];
  const float* T = (const float*)d_in[3];
  float* y = (float*)d_out;

  u16* f2 = (u16*)d_ws;                        // 64*32*4096*4 bf16 = 67,108,864 B
  u16* wcat = (u16*)((char*)d_ws + 67108864);  // 2*128*128 bf16 = 65,536 B

  k0_wcat<<<128, 256, 0, stream>>>(cw, wcat);
  k1_fwht<<<2048, 256, 0, stream>>>(x, f2);
  k2_mix<<<4096, 256, 0, stream>>>(f2, wcat, v, T);
  k3_iwht<<<2048, 256, 0, stream>>>(f2, x, y);
}

// Round 6
// 124.592 us; speedup vs baseline: 1.2398x; 1.2398x over previous
//
#include <hip/hip_runtime.h>

typedef unsigned short u16;
typedef unsigned int u32;
typedef __attribute__((ext_vector_type(8))) __bf16 bf16x8;
typedef __attribute__((ext_vector_type(8))) unsigned short u16x8;
typedef __attribute__((ext_vector_type(2))) unsigned int u32x2;
typedef __attribute__((ext_vector_type(4))) float f32x4;

// ---- bf16 <-> f32 (RNE), bit-exact storage as u16 ----
__device__ __forceinline__ u16 f2bf(float f) {
  u32 u = __builtin_bit_cast(u32, f);
  u += 0x7FFFu + ((u >> 16) & 1u);
  return (u16)(u >> 16);
}
__device__ __forceinline__ float bf2f(u16 h) {
  u32 u = ((u32)h) << 16;
  return __builtin_bit_cast(float, u);
}

// in-register butterfly set over 16 elements, pair mask M
template <int M>
__device__ __forceinline__ void bfly16(float r[16]) {
#pragma unroll
  for (int j = 0; j < 16; ++j)
    if ((j & M) == 0) {
      float a = r[j], b = r[j | M];
      r[j] = a + b;
      r[j | M] = a - b;
    }
}

// ---- K0: conv_w fp32 -> bf16 in MFMA-fragment-major order:
//      wc[frag_id*512 + lane*8 + j], frag_id = ((fp*4+wv)*2+fm)*4+q,
//      lane covers row = fp*128+wv*32+fm*16+(lane&15), k = 32q+8*(lane>>4)+j ----
__global__ __launch_bounds__(256) void k0_wcat(const float* __restrict__ cw,
                                               u16* __restrict__ wc) {
  const int i = blockIdx.x * 256 + threadIdx.x;  // 0..32767
  const int j = i & 7;
  const int lr = (i >> 3) & 15;
  const int lq = (i >> 7) & 3;
  const int q = (i >> 9) & 3;
  const int fm = (i >> 11) & 1;
  const int wv = (i >> 12) & 3;
  const int fp = (i >> 14) & 1;
  const int row = fp * 128 + wv * 32 + fm * 16 + lr;  // p*128 + o
  const int k = q * 32 + lq * 8 + j;
  wc[i] = f2bf(cw[row * 128 + k]);
}

// ---- K1: block = (b, cg): pad + 2D FWHT on 8 channel planes,
//          write f2[b][cg16][pos][c8] -> contiguous 1KB/wave stores ----
__global__ __launch_bounds__(256) void k1_fwht(const float* __restrict__ x,
                                               u16* __restrict__ f2) {
  __shared__ float lds[64 * 68];  // padded stride 68 floats
  const int t = threadIdx.x;
  const int b = blockIdx.x >> 4;
  const int cg = blockIdx.x & 15;
  const int hA = t >> 2, wq = t & 3;   // phase A ownership
  const int hg = t >> 4, rB = t & 15;  // phase B ownership
  const int wC = t & 63, rr = t >> 6;  // phase C ownership
  const bool hok = hA < 56;
  u16x8 outv[16];  // [j][plane], static indexing only

#pragma unroll
  for (int pp = 0; pp < 8; ++pp) {
    const float* xp = x + (size_t)(b * 128 + cg * 8 + pp) * 3136;
    float r[16];
#pragma unroll
    for (int c4 = 0; c4 < 4; ++c4) {
      const int w0 = wq * 16 + c4 * 4;
      if (hok && w0 < 56) {
        const float4 v4 = *(const float4*)(xp + hA * 56 + w0);
        r[c4 * 4 + 0] = v4.x; r[c4 * 4 + 1] = v4.y;
        r[c4 * 4 + 2] = v4.z; r[c4 * 4 + 3] = v4.w;
      } else {
        r[c4 * 4 + 0] = 0.f; r[c4 * 4 + 1] = 0.f;
        r[c4 * 4 + 2] = 0.f; r[c4 * 4 + 3] = 0.f;
      }
    }
    bfly16<1>(r); bfly16<2>(r); bfly16<4>(r); bfly16<8>(r);  // w 1,2,4,8
    if (pp) __syncthreads();  // prior plane's phase-C reads must finish
#pragma unroll
    for (int c4 = 0; c4 < 4; ++c4)
      *(float4*)&lds[hA * 68 + wq * 16 + c4 * 4] =
          make_float4(r[c4 * 4 + 0], r[c4 * 4 + 1], r[c4 * 4 + 2], r[c4 * 4 + 3]);
    __syncthreads();
    // phase B: w stages 16,32 + h stages 1,2
    float q[16];
#pragma unroll
    for (int k = 0; k < 4; ++k)
#pragma unroll
      for (int d = 0; d < 4; ++d)
        q[k * 4 + d] = lds[(hg * 4 + d) * 68 + k * 16 + rB];
    bfly16<4>(q); bfly16<8>(q); bfly16<1>(q); bfly16<2>(q);
#pragma unroll
    for (int k = 0; k < 4; ++k)
#pragma unroll
      for (int d = 0; d < 4; ++d)
        lds[(hg * 4 + d) * 68 + k * 16 + rB] = q[k * 4 + d];  // own addrs
    __syncthreads();
    // phase C: h stages 4,8,16,32
    float s[16];
#pragma unroll
    for (int j = 0; j < 16; ++j) s[j] = lds[(4 * j + rr) * 68 + wC];
    bfly16<1>(s); bfly16<2>(s); bfly16<4>(s); bfly16<8>(s);
#pragma unroll
    for (int j = 0; j < 16; ++j) outv[j][pp] = f2bf(s[j]);
  }
  // f2[b][cg][pos][c8]: lane stores 16B at pos*16B, wC consecutive -> 1KB/instr
  u16* dst = f2 + ((size_t)(b * 16 + cg) << 15);
#pragma unroll
  for (int j = 0; j < 16; ++j) {
    const int pos = (4 * j + rr) * 64 + wC;
    *(u16x8*)(dst + (size_t)pos * 8) = outv[j];
  }
}

// ---- K2: per (b, 64-pos tile): GEMM from global (no LDS) + v-scale +
//          soft-threshold + p-sum, IN-PLACE: f2[b][cg][pos][c8] -> [b][og][pos][o8]
//          Full register prefetch of all A/B fragments for MLP. ----
__global__ __launch_bounds__(256, 2) void k2_mix(u16* __restrict__ fg,
                                                 const u16* __restrict__ wc,
                                                 const float* __restrict__ vv,
                                                 const float* __restrict__ tt) {
  const int t = threadIdx.x;
  const int b = blockIdx.x >> 6;
  const int p0 = (blockIdx.x & 63) << 6;
  u16* fb = fg + ((size_t)b << 19);
  const int wv = t >> 6, l = t & 63, lr = l & 15, lq = l >> 4;

  // ---- prefetch ALL B-fragments (LLC/HBM latency) ----
  bf16x8 bfr[4][4];  // [q][fn]
#pragma unroll
  for (int q = 0; q < 4; ++q)
#pragma unroll
    for (int fn = 0; fn < 4; ++fn)
      bfr[q][fn] = __builtin_bit_cast(
          bf16x8, *(const u16x8*)(fb + ((size_t)(4 * q + lq) << 15) +
                                  (size_t)(p0 + fn * 16 + lr) * 8));
  // ---- prefetch ALL A-fragments (fragment-major wcat: 1KB contiguous/instr) ----
  bf16x8 afr[4][2][2];  // [q][fp][fm]
#pragma unroll
  for (int q = 0; q < 4; ++q)
#pragma unroll
    for (int fp = 0; fp < 2; ++fp)
#pragma unroll
      for (int fm = 0; fm < 2; ++fm) {
        const int frag_id = ((fp * 4 + wv) * 2 + fm) * 4 + q;
        afr[q][fp][fm] = __builtin_bit_cast(
            bf16x8, *(const u16x8*)(wc + (frag_id << 9) + l * 8));
      }
  // ---- epilogue scalars, loaded before the hazard barrier ----
  float v0s[4], v1s[4], t0s[4], t1s[4];
#pragma unroll
  for (int fn = 0; fn < 4; ++fn) {
    const int pos = p0 + fn * 16 + lr;
    v0s[fn] = vv[pos];
    v1s[fn] = vv[4096 + pos];
    t0s[fn] = fmaxf(tt[pos], 0.f);
    t1s[fn] = fmaxf(tt[4096 + pos], 0.f);
  }

  f32x4 acc[2][2][4] = {};  // [fp][fm][fn]
#pragma unroll
  for (int q = 0; q < 4; ++q)
#pragma unroll
    for (int fn = 0; fn < 4; ++fn)
#pragma unroll
      for (int fp = 0; fp < 2; ++fp)
#pragma unroll
        for (int fm = 0; fm < 2; ++fm)
          acc[fp][fm][fn] = __builtin_amdgcn_mfma_f32_16x16x32_bf16(
              afr[q][fp][fm], bfr[q][fn], acc[fp][fm][fn], 0, 0, 0);

  // all waves' reads of this tile drained (vmcnt(0) at barrier) before stores
  __syncthreads();
  // epilogue: v-scale, soft-threshold, p-sum (in-register), b64 stores
#pragma unroll
  for (int fn = 0; fn < 4; ++fn) {
    const int pos = p0 + fn * 16 + lr;  // D col = lane&15
#pragma unroll
    for (int fm = 0; fm < 2; ++fm) {
      u16 w[4];
#pragma unroll
      for (int rg = 0; rg < 4; ++rg) {  // D row = 4*lq+rg -> o = wv*32+fm*16+lq*4+rg
        const float z0 = v0s[fn] * acc[0][fm][fn][rg];
        const float z1 = v1s[fn] * acc[1][fm][fn][rg];
        const float s0v = copysignf(fmaxf(fabsf(z0) - t0s[fn], 0.f), z0);
        const float s1v = copysignf(fmaxf(fabsf(z1) - t1s[fn], 0.f), z1);
        w[rg] = f2bf(s0v + s1v);
      }
      const int og = wv * 4 + fm * 2 + (lq >> 1);  // o>>3
      u32x2 pk;
      pk[0] = (u32)w[0] | ((u32)w[1] << 16);
      pk[1] = (u32)w[2] | ((u32)w[3] << 16);
      *(u32x2*)(fb + ((size_t)og << 15) + (size_t)pos * 8 + (lq & 1) * 4) = pk;
    }
  }
}

// ---- K3: block = (b, og): 8-plane 2D IWHT (x 1/4096) + crop + residual;
//          reads g[b][og][pos][o8] -> 256B contiguous per thread ----
__global__ __launch_bounds__(256) void k3_iwht(const u16* __restrict__ g,
                                               const float* __restrict__ x,
                                               float* __restrict__ y) {
  __shared__ float lds[64 * 68];
  const int t = threadIdx.x;
  const int b = blockIdx.x >> 4;
  const int og = blockIdx.x & 15;
  const u16* gb = g + ((size_t)(b * 16 + og) << 15);
  const int hA = t >> 2, wq = t & 3;
  const int hg = t >> 4, rB = t & 15;
  const int wC = t & 63, rr = t >> 6;
  // preload phase-A ownership for all 8 planes: 16 b128 loads, 256B contiguous
  u16x8 inv[16];
#pragma unroll
  for (int e = 0; e < 16; ++e)
    inv[e] = *(const u16x8*)(gb + (size_t)(hA * 64 + wq * 16 + e) * 8);

#pragma unroll
  for (int pp = 0; pp < 8; ++pp) {
    float r[16];
#pragma unroll
    for (int e = 0; e < 16; ++e) r[e] = bf2f(inv[e][pp]);
    bfly16<1>(r); bfly16<2>(r); bfly16<4>(r); bfly16<8>(r);
    if (pp) __syncthreads();
#pragma unroll
    for (int c4 = 0; c4 < 4; ++c4)
      *(float4*)&lds[hA * 68 + wq * 16 + c4 * 4] =
          make_float4(r[c4 * 4 + 0], r[c4 * 4 + 1], r[c4 * 4 + 2], r[c4 * 4 + 3]);
    __syncthreads();
    float q[16];
#pragma unroll
    for (int k = 0; k < 4; ++k)
#pragma unroll
      for (int d = 0; d < 4; ++d)
        q[k * 4 + d] = lds[(hg * 4 + d) * 68 + k * 16 + rB];
    bfly16<4>(q); bfly16<8>(q); bfly16<1>(q); bfly16<2>(q);
#pragma unroll
    for (int k = 0; k < 4; ++k)
#pragma unroll
      for (int d = 0; d < 4; ++d)
        lds[(hg * 4 + d) * 68 + k * 16 + rB] = q[k * 4 + d];
    __syncthreads();
    float s[16];
#pragma unroll
    for (int j = 0; j < 16; ++j) s[j] = lds[(4 * j + rr) * 68 + wC];
    bfly16<1>(s); bfly16<2>(s); bfly16<4>(s); bfly16<8>(s);
    if (wC < 56) {
      const size_t plane = (size_t)(b * 128 + og * 8 + pp) * 3136;
#pragma unroll
      for (int j = 0; j < 14; ++j) {  // h = 4j+rr <= 55
        const int h = 4 * j + rr;
        const size_t idx = plane + (size_t)(h * 56 + wC);
        y[idx] = x[idx] + s[j] * (1.f / 4096.f);
      }
    }
  }
}

extern "C" void kernel_launch(void* const* d_in, const int* in_sizes, int n_in,
                              void* d_out, int out_size, void* d_ws, size_t ws_size,
                              hipStream_t stream) {
  const float* x = (const float*)d_in[0];
  const float* cw = (const float*)d_in[1];
  const float* v = (const float*)d_in[2];
  const float* T = (const float*)d_in[3];
  float* y = (float*)d_out;

  u16* f2 = (u16*)d_ws;                        // 64*16*4096*8 bf16 = 67,108,864 B
  u16* wcat = (u16*)((char*)d_ws + 67108864);  // 2*128*128 bf16 = 65,536 B

  k0_wcat<<<128, 256, 0, stream>>>(cw, wcat);
  k1_fwht<<<1024, 256, 0, stream>>>(x, f2);
  k2_mix<<<4096, 256, 0, stream>>>(f2, wcat, v, T);
  k3_iwht<<<1024, 256, 0, stream>>>(f2, x, y);
}